// Round 1
// 239.995 us; speedup vs baseline: 1.1493x; 1.1493x over previous
//
#include <hip/hip_runtime.h>
#include <hip/hip_bf16.h>
#include <math.h>

#define BATCH   4
#define N_KP    1024
#define C_DIM   128
#define HW_     256
#define M_CELLS 1024
#define BIGV    10.0f
#define EPSV    1e-8f

typedef __attribute__((ext_vector_type(8))) short short8;
typedef __attribute__((ext_vector_type(4))) float f32x4;

__device__ inline float wsum(float v) {
#pragma unroll
    for (int off = 32; off > 0; off >>= 1) v += __shfl_xor(v, off, 64);
    return v;
}

// branchless insert of x into ascending sorted-8 (keep 8 smallest)
__device__ inline void ins8(float s[8], float x) {
    s[7] = fminf(s[7], x);
#pragma unroll
    for (int t = 7; t >= 1; --t) {
        float lo = fminf(s[t - 1], s[t]);
        float hi = fmaxf(s[t - 1], s[t]);
        s[t - 1] = lo; s[t] = hi;
    }
}

#define CE(a, b) { float _lo = fminf(a, b), _hi = fmaxf(a, b); a = _lo; b = _hi; }

__device__ inline void merge64(float s[8]) {
#pragma unroll
    for (int d = 1; d < 64; d <<= 1) {
        float p[8];
#pragma unroll
        for (int i = 0; i < 8; ++i) p[i] = __shfl_xor(s[i], d, 64);
        float m[8];
#pragma unroll
        for (int i = 0; i < 8; ++i) m[i] = fminf(s[i], p[7 - i]);
        CE(m[0], m[4]); CE(m[1], m[5]); CE(m[2], m[6]); CE(m[3], m[7]);
        CE(m[0], m[2]); CE(m[1], m[3]); CE(m[4], m[6]); CE(m[5], m[7]);
        CE(m[0], m[1]); CE(m[2], m[3]); CE(m[4], m[5]); CE(m[6], m[7]);
#pragma unroll
        for (int i = 0; i < 8; ++i) s[i] = m[i];
    }
}

__device__ inline float packkey(float v, int j) {
    return __uint_as_float((__float_as_uint(v) & 0xFFFFFC00u) | (unsigned)j);
}

__device__ inline unsigned bf16rne(float x) {
    unsigned u = __float_as_uint(x);
    return (u + 0x7FFFu + ((u >> 16) & 1u)) >> 16;
}

// ---------------- K1 (fused prep+gather): direct fp32 gather from desc2 (B,C,H,W) ----------------
// id <  B*N : a=l2n(kp1_desc), aB bf16, wa bilinear-gather -> waB bf16, pos, vis
// id >= B*N : gd lattice gather -> gdB bf16
__global__ __launch_bounds__(64) void k_gath(const float* __restrict__ kdesc,
                                             const float* __restrict__ kp1,
                                             const float* __restrict__ wkp,
                                             const float* __restrict__ homo,
                                             const float* __restrict__ desc2,
                                             float* __restrict__ a,
                                             unsigned* __restrict__ aB,
                                             unsigned* __restrict__ waB,
                                             unsigned* __restrict__ gdB,
                                             float* __restrict__ pos,
                                             float* __restrict__ vis) {
    int id = blockIdx.x;
    int l = threadIdx.x;
    if (id < BATCH * N_KP) {
        int row = id, b = row >> 10;
        // ---- anchor: a = l2n(kp1_desc) (fp32 + bf16 copy) ----
        float2 v = ((const float2*)(kdesc + (size_t)row * C_DIM))[l];
        float ss = wsum(v.x * v.x + v.y * v.y);
        float nrm = sqrtf(ss) + EPSV;
        float a0 = v.x / nrm, a1 = v.y / nrm;
        ((float2*)(a + (size_t)row * C_DIM))[l] = make_float2(a0, a1);
        aB[(size_t)row * 64 + l] = bf16rne(a0) | (bf16rne(a1) << 16);
        // ---- positive: bilinear gather straight from fp32 desc2 ----
        float px = wkp[(size_t)row * 2];
        float py = wkp[(size_t)row * 2 + 1];
        float x = fminf(fmaxf(px, 0.f), (float)(HW_ - 1));
        float y = fminf(fmaxf(py, 0.f), (float)(HW_ - 1));
        float x0f = floorf(x), y0f = floorf(y);
        float wx = x - x0f, wy = y - y0f;
        int x0 = (int)x0f, y0 = (int)y0f;
        int x1 = min(x0 + 1, HW_ - 1), y1 = min(y0 + 1, HW_ - 1);
        float w00 = (1.f - wy) * (1.f - wx);
        float w01 = (1.f - wy) * wx;
        float w10 = wy * (1.f - wx);
        float w11 = wy * wx;
        const float* P0 = desc2 + (size_t)(b * C_DIM + 2 * l) * HW_ * HW_;
        const float* P1 = P0 + (size_t)HW_ * HW_;
        int o00 = y0 * HW_ + x0, o01 = y0 * HW_ + x1;
        int o10 = y1 * HW_ + x0, o11 = y1 * HW_ + x1;
        float g00a = P0[o00], g01a = P0[o01], g10a = P0[o10], g11a = P0[o11];
        float g00b = P1[o00], g01b = P1[o01], g10b = P1[o10], g11b = P1[o11];
        float v0 = g00a * w00 + g01a * w01 + g10a * w10 + g11a * w11;
        float v1 = g00b * w00 + g01b * w01 + g10b * w10 + g11b * w11;
        float s2 = wsum(v0 * v0 + v1 * v1);
        float n2 = sqrtf(s2) + EPSV;
        float wv0 = v0 / n2, wv1 = v1 / n2;
        waB[(size_t)row * 64 + l] = bf16rne(wv0) | (bf16rne(wv1) << 16);
        float d0 = a0 - wv0, d1 = a1 - wv1;
        float pp = wsum(d0 * d0 + d1 * d1);
        if (l == 0) {
            pos[row] = sqrtf(pp);
            // ---- visibility of homography-warped kp1 ----
            float kx = kp1[(size_t)row * 2];
            float ky = kp1[(size_t)row * 2 + 1];
            const float* h = homo + b * 9;
            float u = h[0] * kx + h[1] * ky + h[2];
            float vv = h[3] * kx + h[4] * ky + h[5];
            float w = h[6] * kx + h[7] * ky + h[8];
            float wx_ = u / (w + EPSV);
            float wy_ = vv / (w + EPSV);
            vis[row] = (wx_ >= 0.f && wx_ <= (float)(HW_ - 1) &&
                        wy_ >= 0.f && wy_ <= (float)(HW_ - 1)) ? 1.f : 0.f;
        }
    } else {
        // ---- grid-cell centers: exact integer lattice, pure point read ----
        int idx = id - BATCH * N_KP;
        int b = idx >> 10, m = idx & 1023;
        int x0 = (m & 31) * 8 + 4;
        int y0 = (m >> 5) * 8 + 4;
        const float* P0 = desc2 + (size_t)(b * C_DIM + 2 * l) * HW_ * HW_ + y0 * HW_ + x0;
        float v0 = P0[0];
        float v1 = P0[(size_t)HW_ * HW_];
        float ss = wsum(v0 * v0 + v1 * v1);
        float nrm = sqrtf(ss) + EPSV;
        gdB[(size_t)idx * 64 + l] = bf16rne(v0 / nrm) | (bf16rne(v1 / nrm) << 16);
    }
}

// ---------------- K2: MFMA distance matrix -> global ----------------
// z==0: neg (A=aB, G=gdB);  z==1: d2m (A=waB, G=waB)
// Wave: 16 rows x 64 cols (4 MFMA tiles), block: 4 waves = 16 x 256.
__global__ __launch_bounds__(256, 4) void k_dist(const unsigned* __restrict__ aB,
                                                 const unsigned* __restrict__ waB,
                                                 const unsigned* __restrict__ gdB,
                                                 const float* __restrict__ wkp,
                                                 float* __restrict__ mat) {
    int zsel = blockIdx.z;
    int t = threadIdx.x;
    int lane = t & 63, w = t >> 6;
    int m = lane & 15, q = lane >> 4;           // A-frag row / B-frag col = m; k-quad = q
    int rowT = blockIdx.y;                      // 0..255 (16-row tiles over B*N)
    int b = rowT >> 6;
    int n0 = (rowT & 63) * 16;
    int colBase = blockIdx.x * 256 + w * 64;
    const short* A = (const short*)(zsel == 0 ? aB : waB);
    const short* G = (const short*)(zsel == 0 ? gdB : waB);
    const short* Ar = A + ((size_t)(b * N_KP + n0 + m) * C_DIM + q * 8);
    const short* Gb = G + ((size_t)b * N_KP) * C_DIM + q * 8;
    f32x4 acc[4];
#pragma unroll
    for (int ct = 0; ct < 4; ++ct) acc[ct] = f32x4{0.f, 0.f, 0.f, 0.f};
#pragma unroll
    for (int c = 0; c < C_DIM; c += 32) {
        short8 af = *(const short8*)(Ar + c);
#pragma unroll
        for (int ct = 0; ct < 4; ++ct) {
            short8 bf = *(const short8*)(Gb + (size_t)(colBase + ct * 16 + m) * C_DIM + c);
            acc[ct] = __builtin_amdgcn_mfma_f32_16x16x32_bf16(af, bf, acc[ct], 0, 0, 0);
        }
    }
    // D layout: col = colBase+ct*16+m, row(in-tile) = q*4+r  [m89-verified]
    float2 wrow[4];
#pragma unroll
    for (int r = 0; r < 4; ++r)
        wrow[r] = ((const float2*)wkp)[b * N_KP + n0 + q * 4 + r];
    float* out = mat + (size_t)(zsel * BATCH + b) * N_KP * 1024;
#pragma unroll
    for (int ct = 0; ct < 4; ++ct) {
        int j = colBase + ct * 16 + m;
        float cx, cy;
        if (zsel == 0) {
            cx = (float)(j & 31) * 8.0f + 4.0f;
            cy = (float)(j >> 5) * 8.0f + 4.0f;
        } else {
            float2 wj = ((const float2*)wkp)[b * N_KP + j];
            cx = wj.x; cy = wj.y;
        }
#pragma unroll
        for (int r = 0; r < 4; ++r) {
            int n = n0 + q * 4 + r;
            float d = sqrtf(fmaxf(2.f - 2.f * acc[ct][r], 0.f) + EPSV);
            float dx = wrow[r].x - cx, dy = wrow[r].y - cy;
            if (dx * dx + dy * dy < 256.f || (zsel == 1 && n == j)) d = BIGV;
            out[(size_t)n * 1024 + j] = d;
        }
    }
}

// ---------------- K3: selection + per-row loss -> plain stores ----------------
__global__ __launch_bounds__(256) void k_sel(const float* __restrict__ mat,
                                             const float* __restrict__ a,
                                             const float* __restrict__ pos,
                                             const float* __restrict__ vis,
                                             float* __restrict__ fos_row,
                                             float* __restrict__ sos_row) {
    int zsel = blockIdx.y;
    int r4 = blockIdx.x * 4 + (threadIdx.x >> 6);   // row in [0,4096)
    int b = r4 >> 10;
    int l = threadIdx.x & 63;
    const float4* dr = (const float4*)(mat + (size_t)(zsel * BATCH * N_KP + r4) * 1024);
    float s8[8];
#pragma unroll
    for (int k = 0; k < 8; ++k) s8[k] = 1e30f;
    if (zsel == 0) {
        float4 v0 = dr[l], v1 = dr[l + 64], v2 = dr[l + 128], v3 = dr[l + 192];
        ins8(s8, v0.x); ins8(s8, v0.y); ins8(s8, v0.z); ins8(s8, v0.w);
        ins8(s8, v1.x); ins8(s8, v1.y); ins8(s8, v1.z); ins8(s8, v1.w);
        ins8(s8, v2.x); ins8(s8, v2.y); ins8(s8, v2.z); ins8(s8, v2.w);
        ins8(s8, v3.x); ins8(s8, v3.y); ins8(s8, v3.z); ins8(s8, v3.w);
        merge64(s8);
        if (l == 0) {
            float p = pos[r4];
            float sum = 0.f;
#pragma unroll
            for (int q = 0; q < 8; ++q) sum += fmaxf(p - s8[q] + 1.0f, 0.f);
            fos_row[r4] = sum * vis[r4];
        }
    } else {
#pragma unroll
        for (int k = 0; k < 4; ++k) {
            float4 v = dr[l + 64 * k];
            int j = 4 * (l + 64 * k);
            ins8(s8, packkey(v.x, j));
            ins8(s8, packkey(v.y, j + 1));
            ins8(s8, packkey(v.z, j + 2));
            ins8(s8, packkey(v.w, j + 3));
        }
        merge64(s8);
        float2 av = ((const float2*)(a + (size_t)r4 * C_DIM))[l];
        float dot[8];
#pragma unroll
        for (int q = 0; q < 8; ++q) {
            int j = (int)(__float_as_uint(s8[q]) & 1023u);
            float2 jv = ((const float2*)(a + (size_t)(b * N_KP + j) * C_DIM))[l];
            dot[q] = av.x * jv.x + av.y * jv.y;
        }
#pragma unroll
        for (int q = 0; q < 8; ++q) dot[q] = wsum(dot[q]);
        float ss2 = 0.f;
#pragma unroll
        for (int q = 0; q < 8; ++q) {
            float d2s = __uint_as_float(__float_as_uint(s8[q]) & 0xFFFFFC00u);
            float d1 = sqrtf(fmaxf(2.f - 2.f * dot[q], 0.f) + EPSV);
            float okv = (d2s < 5.0f) ? 1.f : 0.f;
            float diff = (d1 - d2s) * okv;
            ss2 += diff * diff;
        }
        if (l == 0) sos_row[r4] = sqrtf(ss2 + EPSV) * vis[r4];
    }
}

// ---------------- K4: deterministic reduction + finalize (single block) ----------------
__global__ __launch_bounds__(1024) void k_red(const float* __restrict__ vis,
                                              const float* __restrict__ fos_row,
                                              const float* __restrict__ sos_row,
                                              float* __restrict__ out) {
    __shared__ float sb[3][16];
    int t = threadIdx.x;
    float sv = 0.f, sf = 0.f, ss = 0.f;
    for (int i = t; i < BATCH * N_KP; i += 1024) {
        sv += vis[i];
        sf += fos_row[i];
        ss += sos_row[i];
    }
    sv = wsum(sv); sf = wsum(sf); ss = wsum(ss);
    int w = t >> 6, l = t & 63;
    if (l == 0) { sb[0][w] = sv; sb[1][w] = sf; sb[2][w] = ss; }
    __syncthreads();
    if (t == 0) {
        float cv = 0.f, cf = 0.f, cs = 0.f;
#pragma unroll
        for (int i = 0; i < 16; ++i) { cv += sb[0][i]; cf += sb[1][i]; cs += sb[2][i]; }
        float cnt = fmaxf(cv, 1.0f);
        out[0] = cf / (cnt * 8.0f) + cs / cnt;
    }
}

extern "C" void kernel_launch(void* const* d_in, const int* in_sizes, int n_in,
                              void* d_out, int out_size, void* d_ws, size_t ws_size,
                              hipStream_t stream) {
    (void)in_sizes; (void)n_in; (void)out_size; (void)ws_size;
    const float* kp1   = (const float*)d_in[0];
    const float* wkp   = (const float*)d_in[1];
    const float* kdesc = (const float*)d_in[2];
    const float* desc2 = (const float*)d_in[3];
    const float* homo  = (const float*)d_in[4];

    float* ws  = (float*)d_ws;
    float* a   = ws + 16;                               // (B,N,C) fp32, 2 MB
    float* pos = a + (size_t)BATCH * N_KP * C_DIM;
    float* vis = pos + BATCH * N_KP;
    float* fos_row = vis + BATCH * N_KP;
    float* sos_row = fos_row + BATCH * N_KP;
    unsigned* aB  = (unsigned*)(sos_row + BATCH * N_KP);        // (B,N,64) bf16x2, 1 MB
    unsigned* waB = aB + (size_t)BATCH * N_KP * 64;             // 1 MB
    unsigned* gdB = waB + (size_t)BATCH * N_KP * 64;            // 1 MB
    float* mat = (float*)(gdB + (size_t)BATCH * M_CELLS * 64);  // (2,B,N,1024) fp32, 32 MB

    k_gath<<<2 * BATCH * N_KP, 64, 0, stream>>>(kdesc, kp1, wkp, homo, desc2,
                                                a, aB, waB, gdB, pos, vis);
    k_dist<<<dim3(4, 256, 2), 256, 0, stream>>>(aB, waB, gdB, wkp, mat);
    k_sel<<<dim3(N_KP * BATCH / 4, 2), 256, 0, stream>>>(mat, a, pos, vis, fos_row, sos_row);
    k_red<<<1, 1024, 0, stream>>>(vis, fos_row, sos_row, (float*)d_out);
}